// Round 7
// baseline (488.609 us; speedup 1.0000x reference)
//
#include <hip/hip_runtime.h>
#include <math.h>

typedef unsigned short u16;
typedef unsigned int u32;
typedef __bf16 bf16x8 __attribute__((ext_vector_type(8)));
typedef float f32x4 __attribute__((ext_vector_type(4)));

// ---- problem constants ----
#define BB 4
#define CC 384
#define HH 56
#define WW 56
#define GG 12
#define GCC 32
#define KK 9
#define HWD 3136           // H*W
#define NT 12544           // B*H*W tokens
#define HID 1536
#define EPSV 1e-5f

__device__ __forceinline__ float b2f(u16 u) {
  union { float f; u32 u; } c; c.u = ((u32)u) << 16; return c.f;
}
__device__ __forceinline__ u16 f2b(float f) {
  union { float f; u32 u; } c; c.f = f;
  u32 r = c.u + 0x7FFFu + ((c.u >> 16) & 1u);
  return (u16)(r >> 16);
}

// =====================================================================
// Probe: ln1_g[0] == 1.0f exactly. f32 -> first u32 is 0x3F800000;
// bf16 pair (1.0,1.0) -> 0x3F803F80. flag=1 means f32 inputs.
// =====================================================================
__global__ void probe_kernel(const void* __restrict__ g, int* __restrict__ flag) {
  if (threadIdx.x == 0 && blockIdx.x == 0) {
    u32 u = *(const u32*)g;
    *flag = (u == 0x3F800000u) ? 1 : 0;
  }
}

// =====================================================================
// Fused param conversion: 9 vectors -> canonical f32 at fixed offsets.
// =====================================================================
__global__ void convert_params(
    const void* q0, const void* q1, const void* q2, const void* q3,
    const void* q4, const void* q5, const void* q6, const void* q7,
    const void* q8, float* __restrict__ dst, const int* __restrict__ flag) {
  const void* src; int off, n;
  switch (blockIdx.y) {
    case 0: src = q0; off = 0;    n = 384;  break;
    case 1: src = q1; off = 384;  n = 384;  break;
    case 2: src = q2; off = 768;  n = 384;  break;
    case 3: src = q3; off = 1152; n = 384;  break;
    case 4: src = q4; off = 1536; n = 384;  break;
    case 5: src = q5; off = 1920; n = 324;  break;
    case 6: src = q6; off = 2304; n = 384;  break;
    case 7: src = q7; off = 2688; n = 1536; break;
    default: src = q8; off = 4224; n = 384; break;
  }
  int i = blockIdx.x * 256 + threadIdx.x;
  if (i >= n) return;
  float v = (*flag) ? ((const float*)src)[i] : b2f(((const u16*)src)[i]);
  dst[off + i] = v;
}

// =====================================================================
// Fused weight convert+transpose: 5 weights (KxN) -> (NxK) bf16.
// vprojT then omT contiguous (fused 708-row B for GEMM 1).
// =====================================================================
__global__ void convert_weights(
    const void* w0, const void* w1, const void* w2, const void* w3,
    const void* w4, u16* __restrict__ wT, const int* __restrict__ flag) {
  const void* in; u16* out; int K, N;
  switch (blockIdx.y) {
    case 0: in = w0; out = wT;                      K = 384;  N = 384;  break;
    case 1: in = w1; out = wT + 147456;             K = 384;  N = 324;  break;
    case 2: in = w2; out = wT + 147456 + 124416;    K = 384;  N = 384;  break;
    case 3: in = w3; out = wT + 2*147456 + 124416;  K = 384;  N = 1536; break;
    default: in = w4; out = wT + 2*147456 + 124416 + 589824; K = 1536; N = 384; break;
  }
  int idx = blockIdx.x * 256 + threadIdx.x;
  int kq = K >> 2;
  if (idx >= N * kq) return;
  int n = idx / kq;
  int k4 = (idx - n * kq) << 2;
  u16 e[4];
  if (*flag) {
    const float* f = (const float*)in;
#pragma unroll
    for (int r = 0; r < 4; r++) e[r] = f2b(f[(size_t)(k4 + r) * N + n]);
  } else {
    const u16* hh = (const u16*)in;
#pragma unroll
    for (int r = 0; r < 4; r++) e[r] = hh[(size_t)(k4 + r) * N + n];
  }
  uint2 pk;
  pk.x = (u32)e[0] | ((u32)e[1] << 16);
  pk.y = (u32)e[2] | ((u32)e[3] << 16);
  *reinterpret_cast<uint2*>(&out[(size_t)n * K + k4]) = pk;
}

// =====================================================================
// LN1 + NCHW->NHWC transpose. x: (B,C,HW) (bf16|f32) -> tn: (NT,C) bf16
// =====================================================================
__global__ __launch_bounds__(256) void ln1_kernel(
    const void* __restrict__ x, const float* __restrict__ gam,
    const float* __restrict__ bet, u16* __restrict__ tn,
    const int* __restrict__ flag) {
  __shared__ u16 tile[64 * 385];
  const int t = threadIdx.x;
  const int blk = blockIdx.x;
  const int b = blk / 49;
  const int hw0 = (blk - b * 49) * 64;
  const int dtf = *flag;

  const int cofs = t >> 3;        // 0..31
  const int hofs = (t & 7) * 8;   // 0..56
  if (dtf) {
    const float* xf = (const float*)x;
#pragma unroll
    for (int it = 0; it < 12; it++) {
      int cc = it * 32 + cofs;
      size_t base = ((size_t)b * CC + cc) * HWD + hw0 + hofs;
      float4 a0 = *reinterpret_cast<const float4*>(&xf[base]);
      float4 a1 = *reinterpret_cast<const float4*>(&xf[base + 4]);
      tile[(hofs + 0) * 385 + cc] = f2b(a0.x);
      tile[(hofs + 1) * 385 + cc] = f2b(a0.y);
      tile[(hofs + 2) * 385 + cc] = f2b(a0.z);
      tile[(hofs + 3) * 385 + cc] = f2b(a0.w);
      tile[(hofs + 4) * 385 + cc] = f2b(a1.x);
      tile[(hofs + 5) * 385 + cc] = f2b(a1.y);
      tile[(hofs + 6) * 385 + cc] = f2b(a1.z);
      tile[(hofs + 7) * 385 + cc] = f2b(a1.w);
    }
  } else {
    const u16* xh = (const u16*)x;
#pragma unroll
    for (int it = 0; it < 12; it++) {
      int cc = it * 32 + cofs;
      uint4 v = *reinterpret_cast<const uint4*>(
          &xh[((size_t)b * CC + cc) * HWD + hw0 + hofs]);
      u32 uu[4] = {v.x, v.y, v.z, v.w};
#pragma unroll
      for (int r = 0; r < 4; r++) {
        tile[(hofs + 2 * r + 0) * 385 + cc] = (u16)(uu[r] & 0xFFFFu);
        tile[(hofs + 2 * r + 1) * 385 + cc] = (u16)(uu[r] >> 16);
      }
    }
  }
  __syncthreads();

  const int lane = t & 63;
  const int wv = t >> 6;
  for (int tk = wv; tk < 64; tk += 4) {
    float v[6];
    float s = 0.f;
#pragma unroll
    for (int j = 0; j < 6; j++) {
      v[j] = b2f(tile[tk * 385 + j * 64 + lane]);
      s += v[j];
    }
#pragma unroll
    for (int off = 32; off > 0; off >>= 1) s += __shfl_xor(s, off);
    float mu = s * (1.f / 384.f);
    float q = 0.f;
#pragma unroll
    for (int j = 0; j < 6; j++) {
      float d = v[j] - mu;
      q += d * d;
    }
#pragma unroll
    for (int off = 32; off > 0; off >>= 1) q += __shfl_xor(q, off);
    float rs = rsqrtf(q * (1.f / 384.f) + EPSV);
    size_t row = ((size_t)b * HWD + hw0 + tk) * CC;
#pragma unroll
    for (int j = 0; j < 6; j++) {
      int cc = j * 64 + lane;
      float y = (v[j] - mu) * rs * gam[cc] + bet[cc];
      tn[row + cc] = f2b(y);
    }
  }
}

// =====================================================================
// LN2: xp1 (NT,C) bf16 -> y2 (NT,C) bf16. One wave per token.
// =====================================================================
__global__ __launch_bounds__(256) void ln2_kernel(
    const u16* __restrict__ xp1, const float* __restrict__ gam,
    const float* __restrict__ bet, u16* __restrict__ y2) {
  const int tok = blockIdx.x * 4 + (threadIdx.x >> 6);
  const int lane = threadIdx.x & 63;
  const u16* row = xp1 + (size_t)tok * CC;
  float v[6];
  float s = 0.f;
#pragma unroll
  for (int j = 0; j < 6; j++) {
    v[j] = b2f(row[j * 64 + lane]);
    s += v[j];
  }
#pragma unroll
  for (int off = 32; off > 0; off >>= 1) s += __shfl_xor(s, off);
  float mu = s * (1.f / 384.f);
  float q = 0.f;
#pragma unroll
  for (int j = 0; j < 6; j++) {
    float d = v[j] - mu;
    q += d * d;
  }
#pragma unroll
  for (int off = 32; off > 0; off >>= 1) q += __shfl_xor(q, off);
  float rs = rsqrtf(q * (1.f / 384.f) + EPSV);
#pragma unroll
  for (int j = 0; j < 6; j++) {
    int cc = j * 64 + lane;
    y2[(size_t)tok * CC + cc] = f2b((v[j] - mu) * rs * gam[cc] + bet[cc]);
  }
}

// =====================================================================
// DCNv4 sampling (16 lanes/group, 2 ch/lane, om preloaded 7x float4).
// =====================================================================
__global__ __launch_bounds__(256) void dcn_kernel(
    const u16* __restrict__ val, const float* __restrict__ om,
    u16* __restrict__ dcn) {
  const int t = threadIdx.x;
  const int u = blockIdx.x * 16 + (t >> 4);
  const int l = t & 15;
  const int g = u % GG;
  const int bhw = u / GG;
  const int hw = bhw % HWD;
  const int b = bhw / HWD;
  const int wx = hw % WW;
  const int hy = hw / WW;

  const float* o = om + (size_t)bhw * 324 + g * 27;
  float4 q[7];
#pragma unroll
  for (int i = 0; i < 7; i++)
    q[i] = *reinterpret_cast<const float4*>(o + 4 * i);
  float ov[28];
#pragma unroll
  for (int i = 0; i < 7; i++) {
    ov[4 * i + 0] = q[i].x;
    ov[4 * i + 1] = q[i].y;
    ov[4 * i + 2] = q[i].z;
    ov[4 * i + 3] = q[i].w;
  }

  const u16* vb = val + (size_t)b * HWD * CC + g * GCC + l * 2;
  float acc0 = 0.f, acc1 = 0.f;
#pragma unroll
  for (int k = 0; k < KK; k++) {
    float dx = ov[2 * k];
    float dy = ov[2 * k + 1];
    float mw = ov[18 + k];
    float px = (float)(wx + (k % 3) - 1) + dx;
    float py = (float)(hy + (k / 3) - 1) + dy;
    float x0f = floorf(px), y0f = floorf(py);
    float tx = px - x0f, ty = py - y0f;
    int x0 = (int)x0f, y0 = (int)y0f;
    int x1 = x0 + 1, y1 = y0 + 1;
    bool xv0 = (x0 >= 0) && (x0 < WW);
    bool xv1 = (x1 >= 0) && (x1 < WW);
    bool yv0 = (y0 >= 0) && (y0 < HH);
    bool yv1 = (y1 >= 0) && (y1 < HH);
    int xc0 = min(max(x0, 0), WW - 1), xc1 = min(max(x1, 0), WW - 1);
    int yc0 = min(max(y0, 0), HH - 1), yc1 = min(max(y1, 0), HH - 1);
    u32 c00 = *reinterpret_cast<const u32*>(&vb[(size_t)(yc0 * WW + xc0) * CC]);
    u32 c01 = *reinterpret_cast<const u32*>(&vb[(size_t)(yc0 * WW + xc1) * CC]);
    u32 c10 = *reinterpret_cast<const u32*>(&vb[(size_t)(yc1 * WW + xc0) * CC]);
    u32 c11 = *reinterpret_cast<const u32*>(&vb[(size_t)(yc1 * WW + xc1) * CC]);
    float w00 = (yv0 && xv0) ? (1.f - tx) * (1.f - ty) : 0.f;
    float w01 = (yv0 && xv1) ? tx * (1.f - ty) : 0.f;
    float w10 = (yv1 && xv0) ? (1.f - tx) * ty : 0.f;
    float w11 = (yv1 && xv1) ? tx * ty : 0.f;
    float s0 = w00 * b2f((u16)(c00 & 0xFFFFu)) + w01 * b2f((u16)(c01 & 0xFFFFu)) +
               w10 * b2f((u16)(c10 & 0xFFFFu)) + w11 * b2f((u16)(c11 & 0xFFFFu));
    float s1 = w00 * b2f((u16)(c00 >> 16)) + w01 * b2f((u16)(c01 >> 16)) +
               w10 * b2f((u16)(c10 >> 16)) + w11 * b2f((u16)(c11 >> 16));
    acc0 += mw * s0;
    acc1 += mw * s1;
  }
  u32 pk = (u32)f2b(acc0) | ((u32)f2b(acc1) << 16);
  *reinterpret_cast<u32*>(&dcn[(size_t)bhw * CC + g * GCC + l * 2]) = pk;
}

// =====================================================================
// Barrier-free wave-GEMM, tile (MI*16) x (NI*16) per wave, explicit
// 2-stage register double-buffer on the K-loop: prefetch step k+1's
// fragments, then issue step k's MFMA batch -> loads always have a full
// MFMA batch (+ other waves) to hide L2 latency.
// To scale parallelism, split M (B replicated: small weights), not N
// (A replicated: large activations) -- learned from R6 regression.
// MODE 4: fused vproj+om (n<384 -> val bf16 ld384; else om f32 ld324).
// MODE 2: bf16 out (ld 384) + residual from external NCHW x (dtf).
// MODE 0: bf16 out (ld Nn), optional GELU.
// MODE 3: external NCHW out (dtf) + bf16 residual (ld 384); moff.
// =====================================================================
template <int MODE, bool GELU, int MI, int NI>
__global__ __launch_bounds__(256) void wgemm_k(
    const u16* __restrict__ A, const u16* __restrict__ Wt,
    const float* __restrict__ bias, const void* __restrict__ res,
    void* __restrict__ out, void* __restrict__ out2,
    int Mt, int Ntiles, int Nn, int K, int moff,
    const int* __restrict__ flag) {
  const int t = threadIdx.x;
  const int wv = t >> 6;
  const int lane = t & 63;
  const int fr = lane & 15;
  const int quad = lane >> 4;
  const int tile = blockIdx.x * 4 + wv;
  const int mt = tile / Ntiles;
  const int nt = tile - mt * Ntiles;
  if (mt >= Mt) return;
  const int m0 = mt * (MI * 16);
  const int n0 = nt * (NI * 16);
  const int dtf = (MODE == 2 || MODE == 3) ? *flag : 0;

  f32x4 acc[MI][NI];
#pragma unroll
  for (int mi = 0; mi < MI; mi++)
#pragma unroll
    for (int ni = 0; ni < NI; ni++) acc[mi][ni] = f32x4{0.f, 0.f, 0.f, 0.f};

  const u16* Ap = A + (size_t)(m0 + fr) * K + quad * 8;
  const u16* Bp = Wt + (size_t)(n0 + fr) * K + quad * 8;

  bf16x8 a0[MI], b0[NI], a1[MI], b1[NI];
#pragma unroll
  for (int mi = 0; mi < MI; mi++)
    a0[mi] = *reinterpret_cast<const bf16x8*>(Ap + (size_t)(mi * 16) * K);
#pragma unroll
  for (int ni = 0; ni < NI; ni++)
    b0[ni] = *reinterpret_cast<const bf16x8*>(Bp + (size_t)(ni * 16) * K);

  for (int kb = 0; kb < K; kb += 64) {
    // prefetch step kb+32
#pragma unroll
    for (int mi = 0; mi < MI; mi++)
      a1[mi] = *reinterpret_cast<const bf16x8*>(Ap + (size_t)(mi * 16) * K + kb + 32);
#pragma unroll
    for (int ni = 0; ni < NI; ni++)
      b1[ni] = *reinterpret_cast<const bf16x8*>(Bp + (size_t)(ni * 16) * K + kb + 32);
    // MFMA on step kb
#pragma unroll
    for (int mi = 0; mi < MI; mi++)
#pragma unroll
      for (int ni = 0; ni < NI; ni++)
        acc[mi][ni] = __builtin_amdgcn_mfma_f32_16x16x32_bf16(
            a0[mi], b0[ni], acc[mi][ni], 0, 0, 0);
    // prefetch step kb+64
    if (kb + 64 < K) {
#pragma unroll
      for (int mi = 0; mi < MI; mi++)
        a0[mi] = *reinterpret_cast<const bf16x8*>(Ap + (size_t)(mi * 16) * K + kb + 64);
#pragma unroll
      for (int ni = 0; ni < NI; ni++)
        b0[ni] = *reinterpret_cast<const bf16x8*>(Bp + (size_t)(ni * 16) * K + kb + 64);
    }
    // MFMA on step kb+32
#pragma unroll
    for (int mi = 0; mi < MI; mi++)
#pragma unroll
      for (int ni = 0; ni < NI; ni++)
        acc[mi][ni] = __builtin_amdgcn_mfma_f32_16x16x32_bf16(
            a1[mi], b1[ni], acc[mi][ni], 0, 0, 0);
  }

  float bias_v[NI];
#pragma unroll
  for (int ni = 0; ni < NI; ni++) {
    int n = n0 + ni * 16 + fr;
    bias_v[ni] = (n < Nn) ? bias[n] : 0.f;
  }

#pragma unroll
  for (int mi = 0; mi < MI; mi++) {
#pragma unroll
    for (int ni = 0; ni < NI; ni++) {
      int n = n0 + ni * 16 + fr;
      int mbase = m0 + mi * 16 + quad * 4;
      if (MODE == 4) {
        if (n < 384) {
#pragma unroll
          for (int r = 0; r < 4; r++)
            ((u16*)out)[(size_t)(mbase + r) * 384 + n] =
                f2b(acc[mi][ni][r] + bias_v[ni]);
        } else if (n < 708) {
#pragma unroll
          for (int r = 0; r < 4; r++)
            ((float*)out2)[(size_t)(mbase + r) * 324 + (n - 384)] =
                acc[mi][ni][r] + bias_v[ni];
        }
      } else if (MODE == 2) {
        int b = mbase / HWD;
        int hw = mbase - b * HWD;
        float rv[4];
        if (dtf) {
          const float* xf = (const float*)res;
          float4 qq = *reinterpret_cast<const float4*>(
              &xf[((size_t)b * CC + n) * HWD + hw]);
          rv[0] = qq.x; rv[1] = qq.y; rv[2] = qq.z; rv[3] = qq.w;
        } else {
          const u16* xh = (const u16*)res;
          uint2 qq = *reinterpret_cast<const uint2*>(
              &xh[((size_t)b * CC + n) * HWD + hw]);
          rv[0] = b2f((u16)(qq.x & 0xFFFFu));
          rv[1] = b2f((u16)(qq.x >> 16));
          rv[2] = b2f((u16)(qq.y & 0xFFFFu));
          rv[3] = b2f((u16)(qq.y >> 16));
        }
#pragma unroll
        for (int r = 0; r < 4; r++)
          ((u16*)out)[(size_t)(mbase + r) * 384 + n] =
              f2b(acc[mi][ni][r] + bias_v[ni] + rv[r]);
      } else if (MODE == 3) {
        const u16* rf = (const u16*)res;
        int mg = mbase + moff;
        int b = mg / HWD;
        int hw = mg - b * HWD;
        float vv[4];
#pragma unroll
        for (int r = 0; r < 4; r++)
          vv[r] = acc[mi][ni][r] + bias_v[ni] + b2f(rf[(size_t)(mg + r) * 384 + n]);
        if (dtf) {
          float4 st = make_float4(vv[0], vv[1], vv[2], vv[3]);
          *reinterpret_cast<float4*>(
              &((float*)out)[((size_t)b * CC + n) * HWD + hw]) = st;
        } else {
          uint2 st;
          st.x = (u32)f2b(vv[0]) | ((u32)f2b(vv[1]) << 16);
          st.y = (u32)f2b(vv[2]) | ((u32)f2b(vv[3]) << 16);
          *reinterpret_cast<uint2*>(
              &((u16*)out)[((size_t)b * CC + n) * HWD + hw]) = st;
        }
      } else {  // MODE 0
#pragma unroll
        for (int r = 0; r < 4; r++) {
          float vv = acc[mi][ni][r] + bias_v[ni];
          if (GELU) vv = 0.5f * vv * (1.0f + erff(vv * 0.70710678118654752f));
          if (n < Nn)
            ((u16*)out)[(size_t)(mbase + r) * Nn + n] = f2b(vv);
        }
      }
    }
  }
}

// =====================================================================
extern "C" void kernel_launch(void* const* d_in, const int* in_sizes, int n_in,
                              void* d_out, int out_size, void* d_ws,
                              size_t ws_size, hipStream_t stream) {
  const void* x = d_in[0];
  const void* ln1_g = d_in[1];
  const void* ln1_b = d_in[2];
  const void* vproj_w = d_in[3];
  const void* vproj_b = d_in[4];
  const void* om_w = d_in[5];
  const void* om_b = d_in[6];
  const void* oproj_w = d_in[7];
  const void* oproj_b = d_in[8];
  const void* ln2_g = d_in[9];
  const void* ln2_b = d_in[10];
  const void* fc1_w = d_in[11];
  const void* fc1_b = d_in[12];
  const void* fc2_w = d_in[13];
  const void* fc2_b = d_in[14];

  char* ws = (char*)d_ws;
  const size_t SZ_NC2 = (size_t)NT * CC * 2;         // 9,633,792
  const size_t SZ_OM4 = (size_t)NT * 324 * 4;        // 16,257,024
  u16* tn = (u16*)(ws);
  u16* dcn = tn;
  u16* y2 = tn;
  u16* val = (u16*)(ws + SZ_NC2);
  u16* h = val;                         // chunk h (19.3MB) spans R1+R2
  float* om = (float*)(ws + 2 * SZ_NC2);
  u16* xp1 = (u16*)(ws + 2 * SZ_NC2 + SZ_OM4);
  u16* wT = (u16*)(ws + 3 * SZ_NC2 + SZ_OM4);
  u16* vprojT = wT;                     // fused (708,384) B matrix
  u16* oprojT = wT + 147456 + 124416;
  u16* fc1T = oprojT + 147456;
  u16* fc2T = fc1T + 589824;
  char* r5 = ws + 3 * SZ_NC2 + SZ_OM4 + 3197952;
  int* flag = (int*)r5;
  float* pf = (float*)r5 + 16;
  float* ln1_gF = pf + 0;
  float* ln1_bF = pf + 384;
  float* ln2_gF = pf + 768;
  float* ln2_bF = pf + 1152;
  float* vom_bF = pf + 1536;
  float* oproj_bF = pf + 2304;
  float* fc1_bF = pf + 2688;
  float* fc2_bF = pf + 4224;

  probe_kernel<<<1, 64, 0, stream>>>(ln1_g, flag);

  convert_params<<<dim3(6, 9), 256, 0, stream>>>(
      ln1_g, ln1_b, ln2_g, ln2_b, vproj_b, om_b, oproj_b, fc1_b, fc2_b,
      pf, flag);

  convert_weights<<<dim3(576, 5), 256, 0, stream>>>(
      vproj_w, om_w, oproj_w, fc1_w, fc2_w, wT, flag);

  ln1_kernel<<<BB * 49, 256, 0, stream>>>(x, ln1_gF, ln1_bF, tn, flag);

  // fused vproj+om: 64x64 tiles, Mt=196, Ntiles=12 -> 2352 tiles, 588 blocks
  wgemm_k<4, false, 4, 4><<<588, 256, 0, stream>>>(
      tn, vprojT, vom_bF, nullptr, val, om, 196, 12, 708, 384, 0, flag);

  dcn_kernel<<<(NT * GG) / 16, 256, 0, stream>>>(val, om, dcn);

  // oproj: 32x64 tiles, Mt=392, Ntiles=6 -> 2352 tiles, 588 blocks
  wgemm_k<2, false, 2, 4><<<588, 256, 0, stream>>>(
      dcn, oprojT, oproj_bF, x, xp1, nullptr, 392, 6, 384, 384, 0, flag);

  ln2_kernel<<<NT / 4, 256, 0, stream>>>(xp1, ln2_gF, ln2_bF, y2);

  // fc1 + fc2 in 2 M-chunks of 6272 rows; h overlays R1+R2
  for (int c = 0; c < 2; c++) {
    int r0 = c * 6272;
    // fc1: 64x64 tiles, Mt=98, Ntiles=24 -> 2352 tiles, 588 blocks
    wgemm_k<0, true, 4, 4><<<588, 256, 0, stream>>>(
        y2 + (size_t)r0 * CC, fc1T, fc1_bF, nullptr, h, nullptr,
        98, 24, HID, 384, 0, flag);
    // fc2: 16x64 tiles (M-split), Mt=392, Ntiles=6 -> 2352 tiles, 588 blocks
    wgemm_k<3, false, 1, 4><<<588, 256, 0, stream>>>(
        h, fc2T, fc2_bF, xp1, d_out, nullptr, 392, 6, 384, HID, r0, flag);
  }
}

// Round 8
// 446.127 us; speedup vs baseline: 1.0952x; 1.0952x over previous
//
#include <hip/hip_runtime.h>
#include <math.h>

typedef unsigned short u16;
typedef unsigned int u32;
typedef __bf16 bf16x8 __attribute__((ext_vector_type(8)));
typedef float f32x4 __attribute__((ext_vector_type(4)));

// ---- problem constants ----
#define BB 4
#define CC 384
#define HH 56
#define WW 56
#define GG 12
#define GCC 32
#define KK 9
#define HWD 3136           // H*W
#define NT 12544           // B*H*W tokens
#define HID 1536
#define EPSV 1e-5f

__device__ __forceinline__ float b2f(u16 u) {
  union { float f; u32 u; } c; c.u = ((u32)u) << 16; return c.f;
}
__device__ __forceinline__ u16 f2b(float f) {
  union { float f; u32 u; } c; c.f = f;
  u32 r = c.u + 0x7FFFu + ((c.u >> 16) & 1u);
  return (u16)(r >> 16);
}

// =====================================================================
// Probe: ln1_g[0] == 1.0f exactly -> f32 inputs (flag=1) else bf16.
// =====================================================================
__global__ void probe_kernel(const void* __restrict__ g, int* __restrict__ flag) {
  if (threadIdx.x == 0 && blockIdx.x == 0) {
    u32 u = *(const u32*)g;
    *flag = (u == 0x3F800000u) ? 1 : 0;
  }
}

// =====================================================================
// Fused param conversion -> canonical f32 at fixed offsets.
// =====================================================================
__global__ void convert_params(
    const void* q0, const void* q1, const void* q2, const void* q3,
    const void* q4, const void* q5, const void* q6, const void* q7,
    const void* q8, float* __restrict__ dst, const int* __restrict__ flag) {
  const void* src; int off, n;
  switch (blockIdx.y) {
    case 0: src = q0; off = 0;    n = 384;  break;
    case 1: src = q1; off = 384;  n = 384;  break;
    case 2: src = q2; off = 768;  n = 384;  break;
    case 3: src = q3; off = 1152; n = 384;  break;
    case 4: src = q4; off = 1536; n = 384;  break;
    case 5: src = q5; off = 1920; n = 324;  break;
    case 6: src = q6; off = 2304; n = 384;  break;
    case 7: src = q7; off = 2688; n = 1536; break;
    default: src = q8; off = 4224; n = 384; break;
  }
  int i = blockIdx.x * 256 + threadIdx.x;
  if (i >= n) return;
  float v = (*flag) ? ((const float*)src)[i] : b2f(((const u16*)src)[i]);
  dst[off + i] = v;
}

// =====================================================================
// Fused weight convert+transpose: 5 weights (KxN) -> (NxK) bf16.
// =====================================================================
__global__ void convert_weights(
    const void* w0, const void* w1, const void* w2, const void* w3,
    const void* w4, u16* __restrict__ wT, const int* __restrict__ flag) {
  const void* in; u16* out; int K, N;
  switch (blockIdx.y) {
    case 0: in = w0; out = wT;                      K = 384;  N = 384;  break;
    case 1: in = w1; out = wT + 147456;             K = 384;  N = 324;  break;
    case 2: in = w2; out = wT + 147456 + 124416;    K = 384;  N = 384;  break;
    case 3: in = w3; out = wT + 2*147456 + 124416;  K = 384;  N = 1536; break;
    default: in = w4; out = wT + 2*147456 + 124416 + 589824; K = 1536; N = 384; break;
  }
  int idx = blockIdx.x * 256 + threadIdx.x;
  int kq = K >> 2;
  if (idx >= N * kq) return;
  int n = idx / kq;
  int k4 = (idx - n * kq) << 2;
  u16 e[4];
  if (*flag) {
    const float* f = (const float*)in;
#pragma unroll
    for (int r = 0; r < 4; r++) e[r] = f2b(f[(size_t)(k4 + r) * N + n]);
  } else {
    const u16* hh = (const u16*)in;
#pragma unroll
    for (int r = 0; r < 4; r++) e[r] = hh[(size_t)(k4 + r) * N + n];
  }
  uint2 pk;
  pk.x = (u32)e[0] | ((u32)e[1] << 16);
  pk.y = (u32)e[2] | ((u32)e[3] << 16);
  *reinterpret_cast<uint2*>(&out[(size_t)n * K + k4]) = pk;
}

// =====================================================================
// LN1 + NCHW->NHWC transpose.
// =====================================================================
__global__ __launch_bounds__(256) void ln1_kernel(
    const void* __restrict__ x, const float* __restrict__ gam,
    const float* __restrict__ bet, u16* __restrict__ tn,
    const int* __restrict__ flag) {
  __shared__ u16 tile[64 * 385];
  const int t = threadIdx.x;
  const int blk = blockIdx.x;
  const int b = blk / 49;
  const int hw0 = (blk - b * 49) * 64;
  const int dtf = *flag;

  const int cofs = t >> 3;
  const int hofs = (t & 7) * 8;
  if (dtf) {
    const float* xf = (const float*)x;
#pragma unroll
    for (int it = 0; it < 12; it++) {
      int cc = it * 32 + cofs;
      size_t base = ((size_t)b * CC + cc) * HWD + hw0 + hofs;
      float4 a0 = *reinterpret_cast<const float4*>(&xf[base]);
      float4 a1 = *reinterpret_cast<const float4*>(&xf[base + 4]);
      tile[(hofs + 0) * 385 + cc] = f2b(a0.x);
      tile[(hofs + 1) * 385 + cc] = f2b(a0.y);
      tile[(hofs + 2) * 385 + cc] = f2b(a0.z);
      tile[(hofs + 3) * 385 + cc] = f2b(a0.w);
      tile[(hofs + 4) * 385 + cc] = f2b(a1.x);
      tile[(hofs + 5) * 385 + cc] = f2b(a1.y);
      tile[(hofs + 6) * 385 + cc] = f2b(a1.z);
      tile[(hofs + 7) * 385 + cc] = f2b(a1.w);
    }
  } else {
    const u16* xh = (const u16*)x;
#pragma unroll
    for (int it = 0; it < 12; it++) {
      int cc = it * 32 + cofs;
      uint4 v = *reinterpret_cast<const uint4*>(
          &xh[((size_t)b * CC + cc) * HWD + hw0 + hofs]);
      u32 uu[4] = {v.x, v.y, v.z, v.w};
#pragma unroll
      for (int r = 0; r < 4; r++) {
        tile[(hofs + 2 * r + 0) * 385 + cc] = (u16)(uu[r] & 0xFFFFu);
        tile[(hofs + 2 * r + 1) * 385 + cc] = (u16)(uu[r] >> 16);
      }
    }
  }
  __syncthreads();

  const int lane = t & 63;
  const int wv = t >> 6;
  for (int tk = wv; tk < 64; tk += 4) {
    float v[6];
    float s = 0.f;
#pragma unroll
    for (int j = 0; j < 6; j++) {
      v[j] = b2f(tile[tk * 385 + j * 64 + lane]);
      s += v[j];
    }
#pragma unroll
    for (int off = 32; off > 0; off >>= 1) s += __shfl_xor(s, off);
    float mu = s * (1.f / 384.f);
    float q = 0.f;
#pragma unroll
    for (int j = 0; j < 6; j++) {
      float d = v[j] - mu;
      q += d * d;
    }
#pragma unroll
    for (int off = 32; off > 0; off >>= 1) q += __shfl_xor(q, off);
    float rs = rsqrtf(q * (1.f / 384.f) + EPSV);
    size_t row = ((size_t)b * HWD + hw0 + tk) * CC;
#pragma unroll
    for (int j = 0; j < 6; j++) {
      int cc = j * 64 + lane;
      float y = (v[j] - mu) * rs * gam[cc] + bet[cc];
      tn[row + cc] = f2b(y);
    }
  }
}

// =====================================================================
// LN2: xp1 (NT,C) bf16 -> y2 bf16. One wave per token.
// =====================================================================
__global__ __launch_bounds__(256) void ln2_kernel(
    const u16* __restrict__ xp1, const float* __restrict__ gam,
    const float* __restrict__ bet, u16* __restrict__ y2) {
  const int tok = blockIdx.x * 4 + (threadIdx.x >> 6);
  const int lane = threadIdx.x & 63;
  const u16* row = xp1 + (size_t)tok * CC;
  float v[6];
  float s = 0.f;
#pragma unroll
  for (int j = 0; j < 6; j++) {
    v[j] = b2f(row[j * 64 + lane]);
    s += v[j];
  }
#pragma unroll
  for (int off = 32; off > 0; off >>= 1) s += __shfl_xor(s, off);
  float mu = s * (1.f / 384.f);
  float q = 0.f;
#pragma unroll
  for (int j = 0; j < 6; j++) {
    float d = v[j] - mu;
    q += d * d;
  }
#pragma unroll
  for (int off = 32; off > 0; off >>= 1) q += __shfl_xor(q, off);
  float rs = rsqrtf(q * (1.f / 384.f) + EPSV);
#pragma unroll
  for (int j = 0; j < 6; j++) {
    int cc = j * 64 + lane;
    y2[(size_t)tok * CC + cc] = f2b((v[j] - mu) * rs * gam[cc] + bet[cc]);
  }
}

// =====================================================================
// DCNv4 sampling. om now bf16, padded layout: token stride 336, group
// stride 28 (27 used). 16 lanes/group, 2 ch/lane.
// =====================================================================
__global__ __launch_bounds__(256) void dcn_kernel(
    const u16* __restrict__ val, const u16* __restrict__ om,
    u16* __restrict__ dcn) {
  const int t = threadIdx.x;
  const int u = blockIdx.x * 16 + (t >> 4);
  const int l = t & 15;
  const int g = u % GG;
  const int bhw = u / GG;
  const int hw = bhw % HWD;
  const int b = bhw / HWD;
  const int wx = hw % WW;
  const int hy = hw / WW;

  const u16* o = om + (size_t)bhw * 336 + g * 28;
  uint2 q[7];
#pragma unroll
  for (int i = 0; i < 7; i++)
    q[i] = *reinterpret_cast<const uint2*>(o + 4 * i);
  float ov[28];
#pragma unroll
  for (int i = 0; i < 7; i++) {
    ov[4 * i + 0] = b2f((u16)(q[i].x & 0xFFFFu));
    ov[4 * i + 1] = b2f((u16)(q[i].x >> 16));
    ov[4 * i + 2] = b2f((u16)(q[i].y & 0xFFFFu));
    ov[4 * i + 3] = b2f((u16)(q[i].y >> 16));
  }

  const u16* vb = val + (size_t)b * HWD * CC + g * GCC + l * 2;
  float acc0 = 0.f, acc1 = 0.f;
#pragma unroll
  for (int k = 0; k < KK; k++) {
    float dx = ov[2 * k];
    float dy = ov[2 * k + 1];
    float mw = ov[18 + k];
    float px = (float)(wx + (k % 3) - 1) + dx;
    float py = (float)(hy + (k / 3) - 1) + dy;
    float x0f = floorf(px), y0f = floorf(py);
    float tx = px - x0f, ty = py - y0f;
    int x0 = (int)x0f, y0 = (int)y0f;
    int x1 = x0 + 1, y1 = y0 + 1;
    bool xv0 = (x0 >= 0) && (x0 < WW);
    bool xv1 = (x1 >= 0) && (x1 < WW);
    bool yv0 = (y0 >= 0) && (y0 < HH);
    bool yv1 = (y1 >= 0) && (y1 < HH);
    int xc0 = min(max(x0, 0), WW - 1), xc1 = min(max(x1, 0), WW - 1);
    int yc0 = min(max(y0, 0), HH - 1), yc1 = min(max(y1, 0), HH - 1);
    u32 c00 = *reinterpret_cast<const u32*>(&vb[(size_t)(yc0 * WW + xc0) * CC]);
    u32 c01 = *reinterpret_cast<const u32*>(&vb[(size_t)(yc0 * WW + xc1) * CC]);
    u32 c10 = *reinterpret_cast<const u32*>(&vb[(size_t)(yc1 * WW + xc0) * CC]);
    u32 c11 = *reinterpret_cast<const u32*>(&vb[(size_t)(yc1 * WW + xc1) * CC]);
    float w00 = (yv0 && xv0) ? (1.f - tx) * (1.f - ty) : 0.f;
    float w01 = (yv0 && xv1) ? tx * (1.f - ty) : 0.f;
    float w10 = (yv1 && xv0) ? (1.f - tx) * ty : 0.f;
    float w11 = (yv1 && xv1) ? tx * ty : 0.f;
    float s0 = w00 * b2f((u16)(c00 & 0xFFFFu)) + w01 * b2f((u16)(c01 & 0xFFFFu)) +
               w10 * b2f((u16)(c10 & 0xFFFFu)) + w11 * b2f((u16)(c11 & 0xFFFFu));
    float s1 = w00 * b2f((u16)(c00 >> 16)) + w01 * b2f((u16)(c01 >> 16)) +
               w10 * b2f((u16)(c10 >> 16)) + w11 * b2f((u16)(c11 >> 16));
    acc0 += mw * s0;
    acc1 += mw * s1;
  }
  u32 pk = (u32)f2b(acc0) | ((u32)f2b(acc1) << 16);
  *reinterpret_cast<u32*>(&dcn[(size_t)bhw * CC + g * GCC + l * 2]) = pk;
}

// =====================================================================
// fc2 K-split epilogue: xp2 (rows,384) f32 -> out NCHW (dtf) with bias
// + xp1 residual. Tile 64m x 64n via LDS transpose. grid (98, 6).
// =====================================================================
__global__ __launch_bounds__(256) void fc2_epi_kernel(
    const float* __restrict__ xp2, const float* __restrict__ bias,
    const u16* __restrict__ xp1, void* __restrict__ out,
    int moff, const int* __restrict__ flag) {
  __shared__ float tile[64][65];
  const int t = threadIdx.x;
  const int m0 = blockIdx.x * 64;
  const int n0 = blockIdx.y * 64;
  const int r = t >> 2;
  const int c0 = (t & 3) * 16;
  const float* src = xp2 + (size_t)(m0 + r) * 384 + n0 + c0;
  const u16* resi = xp1 + (size_t)(m0 + moff + r) * 384 + n0 + c0;
#pragma unroll
  for (int i = 0; i < 4; i++) {
    float4 v = *reinterpret_cast<const float4*>(src + i * 4);
    uint2 rb = *reinterpret_cast<const uint2*>(resi + i * 4);
    float4 bb = *reinterpret_cast<const float4*>(&bias[n0 + c0 + i * 4]);
    tile[c0 + i * 4 + 0][r] = v.x + bb.x + b2f((u16)(rb.x & 0xFFFFu));
    tile[c0 + i * 4 + 1][r] = v.y + bb.y + b2f((u16)(rb.x >> 16));
    tile[c0 + i * 4 + 2][r] = v.z + bb.z + b2f((u16)(rb.y & 0xFFFFu));
    tile[c0 + i * 4 + 3][r] = v.w + bb.w + b2f((u16)(rb.y >> 16));
  }
  __syncthreads();
  const int hwl = t & 63;
  const int ns = t >> 6;
  int mg = m0 + moff;
  int b = mg / HWD;
  int hw = mg - b * HWD + hwl;
  const int dtf = *flag;
  if (dtf) {
    float* o = (float*)out;
#pragma unroll
    for (int j = 0; j < 16; j++) {
      int nl = ns + j * 4;
      o[((size_t)b * CC + n0 + nl) * HWD + hw] = tile[nl][hwl];
    }
  } else {
    u16* o = (u16*)out;
#pragma unroll
    for (int j = 0; j < 16; j++) {
      int nl = ns + j * 4;
      o[((size_t)b * CC + n0 + nl) * HWD + hw] = f2b(tile[nl][hwl]);
    }
  }
}

// =====================================================================
// Barrier-free wave-GEMM, tile (MI*16)x(NI*16) per wave, 2-stage
// register double-buffer K-loop. Fat tiles (64x64) proven best (R5/R6).
// MODE 4: fused vproj+om (n<384 -> val bf16 ld384; else om bf16 padded).
// MODE 2: bf16 out (ld 384) + residual from external NCHW x (dtf).
// MODE 0: bf16 out (ld Nn), optional GELU.
// MODE 3: external NCHW out (dtf) + bf16 residual (ld 384); moff.
// MODE 5: K-split partial -> unsafeAtomicAdd f32 (out stride 384);
//         K-range = [blockIdx.y*384, +384). No bias (epilogue adds).
// =====================================================================
template <int MODE, bool GELU, int MI, int NI>
__global__ __launch_bounds__(256) void wgemm_k(
    const u16* __restrict__ A, const u16* __restrict__ Wt,
    const float* __restrict__ bias, const void* __restrict__ res,
    void* __restrict__ out, void* __restrict__ out2,
    int Mt, int Ntiles, int Nn, int K, int moff,
    const int* __restrict__ flag) {
  const int t = threadIdx.x;
  const int wv = t >> 6;
  const int lane = t & 63;
  const int fr = lane & 15;
  const int quad = lane >> 4;
  const int tile = blockIdx.x * 4 + wv;
  const int mt = tile / Ntiles;
  const int nt = tile - mt * Ntiles;
  if (mt >= Mt) return;
  const int m0 = mt * (MI * 16);
  const int n0 = nt * (NI * 16);
  const int dtf = (MODE == 2 || MODE == 3) ? *flag : 0;
  const int k0 = (MODE == 5) ? (int)blockIdx.y * 384 : 0;
  const int kspan = (MODE == 5) ? 384 : K;

  f32x4 acc[MI][NI];
#pragma unroll
  for (int mi = 0; mi < MI; mi++)
#pragma unroll
    for (int ni = 0; ni < NI; ni++) acc[mi][ni] = f32x4{0.f, 0.f, 0.f, 0.f};

  const u16* Ap = A + (size_t)(m0 + fr) * K + quad * 8 + k0;
  const u16* Bp = Wt + (size_t)(n0 + fr) * K + quad * 8 + k0;

  bf16x8 a0[MI], b0[NI], a1[MI], b1[NI];
#pragma unroll
  for (int mi = 0; mi < MI; mi++)
    a0[mi] = *reinterpret_cast<const bf16x8*>(Ap + (size_t)(mi * 16) * K);
#pragma unroll
  for (int ni = 0; ni < NI; ni++)
    b0[ni] = *reinterpret_cast<const bf16x8*>(Bp + (size_t)(ni * 16) * K);

  for (int kb = 0; kb < kspan; kb += 64) {
#pragma unroll
    for (int mi = 0; mi < MI; mi++)
      a1[mi] = *reinterpret_cast<const bf16x8*>(Ap + (size_t)(mi * 16) * K + kb + 32);
#pragma unroll
    for (int ni = 0; ni < NI; ni++)
      b1[ni] = *reinterpret_cast<const bf16x8*>(Bp + (size_t)(ni * 16) * K + kb + 32);
#pragma unroll
    for (int mi = 0; mi < MI; mi++)
#pragma unroll
      for (int ni = 0; ni < NI; ni++)
        acc[mi][ni] = __builtin_amdgcn_mfma_f32_16x16x32_bf16(
            a0[mi], b0[ni], acc[mi][ni], 0, 0, 0);
    if (kb + 64 < kspan) {
#pragma unroll
      for (int mi = 0; mi < MI; mi++)
        a0[mi] = *reinterpret_cast<const bf16x8*>(Ap + (size_t)(mi * 16) * K + kb + 64);
#pragma unroll
      for (int ni = 0; ni < NI; ni++)
        b0[ni] = *reinterpret_cast<const bf16x8*>(Bp + (size_t)(ni * 16) * K + kb + 64);
    }
#pragma unroll
    for (int mi = 0; mi < MI; mi++)
#pragma unroll
      for (int ni = 0; ni < NI; ni++)
        acc[mi][ni] = __builtin_amdgcn_mfma_f32_16x16x32_bf16(
            a1[mi], b1[ni], acc[mi][ni], 0, 0, 0);
  }

  float bias_v[NI];
#pragma unroll
  for (int ni = 0; ni < NI; ni++) {
    int n = n0 + ni * 16 + fr;
    bias_v[ni] = (MODE != 5 && n < Nn) ? bias[n] : 0.f;
  }

#pragma unroll
  for (int mi = 0; mi < MI; mi++) {
#pragma unroll
    for (int ni = 0; ni < NI; ni++) {
      int n = n0 + ni * 16 + fr;
      int mbase = m0 + mi * 16 + quad * 4;
      if (MODE == 5) {
        float* op = (float*)out;
#pragma unroll
        for (int r = 0; r < 4; r++)
          unsafeAtomicAdd(&op[(size_t)(mbase + r) * 384 + n], acc[mi][ni][r]);
      } else if (MODE == 4) {
        if (n < 384) {
#pragma unroll
          for (int r = 0; r < 4; r++)
            ((u16*)out)[(size_t)(mbase + r) * 384 + n] =
                f2b(acc[mi][ni][r] + bias_v[ni]);
        } else if (n < 708) {
          int lin = n - 384;
          int g = lin / 27;
          int s = lin - g * 27;
#pragma unroll
          for (int r = 0; r < 4; r++)
            ((u16*)out2)[(size_t)(mbase + r) * 336 + g * 28 + s] =
                f2b(acc[mi][ni][r] + bias_v[ni]);
        }
      } else if (MODE == 2) {
        int b = mbase / HWD;
        int hw = mbase - b * HWD;
        float rv[4];
        if (dtf) {
          const float* xf = (const float*)res;
          float4 qq = *reinterpret_cast<const float4*>(
              &xf[((size_t)b * CC + n) * HWD + hw]);
          rv[0] = qq.x; rv[1] = qq.y; rv[2] = qq.z; rv[3] = qq.w;
        } else {
          const u16* xh = (const u16*)res;
          uint2 qq = *reinterpret_cast<const uint2*>(
              &xh[((size_t)b * CC + n) * HWD + hw]);
          rv[0] = b2f((u16)(qq.x & 0xFFFFu));
          rv[1] = b2f((u16)(qq.x >> 16));
          rv[2] = b2f((u16)(qq.y & 0xFFFFu));
          rv[3] = b2f((u16)(qq.y >> 16));
        }
#pragma unroll
        for (int r = 0; r < 4; r++)
          ((u16*)out)[(size_t)(mbase + r) * 384 + n] =
              f2b(acc[mi][ni][r] + bias_v[ni] + rv[r]);
      } else if (MODE == 3) {
        const u16* rf = (const u16*)res;
        int mg = mbase + moff;
        int b = mg / HWD;
        int hw = mg - b * HWD;
        float vv[4];
#pragma unroll
        for (int r = 0; r < 4; r++)
          vv[r] = acc[mi][ni][r] + bias_v[ni] + b2f(rf[(size_t)(mg + r) * 384 + n]);
        if (dtf) {
          float4 st = make_float4(vv[0], vv[1], vv[2], vv[3]);
          *reinterpret_cast<float4*>(
              &((float*)out)[((size_t)b * CC + n) * HWD + hw]) = st;
        } else {
          uint2 st;
          st.x = (u32)f2b(vv[0]) | ((u32)f2b(vv[1]) << 16);
          st.y = (u32)f2b(vv[2]) | ((u32)f2b(vv[3]) << 16);
          *reinterpret_cast<uint2*>(
              &((u16*)out)[((size_t)b * CC + n) * HWD + hw]) = st;
        }
      } else {  // MODE 0
#pragma unroll
        for (int r = 0; r < 4; r++) {
          float vv = acc[mi][ni][r] + bias_v[ni];
          if (GELU) vv = 0.5f * vv * (1.0f + erff(vv * 0.70710678118654752f));
          if (n < Nn)
            ((u16*)out)[(size_t)(mbase + r) * Nn + n] = f2b(vv);
        }
      }
    }
  }
}

// =====================================================================
extern "C" void kernel_launch(void* const* d_in, const int* in_sizes, int n_in,
                              void* d_out, int out_size, void* d_ws,
                              size_t ws_size, hipStream_t stream) {
  const void* x = d_in[0];
  const void* ln1_g = d_in[1];
  const void* ln1_b = d_in[2];
  const void* vproj_w = d_in[3];
  const void* vproj_b = d_in[4];
  const void* om_w = d_in[5];
  const void* om_b = d_in[6];
  const void* oproj_w = d_in[7];
  const void* oproj_b = d_in[8];
  const void* ln2_g = d_in[9];
  const void* ln2_b = d_in[10];
  const void* fc1_w = d_in[11];
  const void* fc1_b = d_in[12];
  const void* fc2_w = d_in[13];
  const void* fc2_b = d_in[14];

  char* ws = (char*)d_ws;
  const size_t SZ_NC2 = (size_t)NT * CC * 2;   // 9,633,792
  // R0 [0,NC2): tn -> dcn -> y2
  // R1 [NC2,2NC2): val -> h-chunk low half
  // R2 [2NC2,3NC2): om bf16 padded (8.43MB used) -> h-chunk high half
  // R3 [3NC2,4NC2): xp1 bf16
  // R4: weights bf16 (3,197,952 B)
  // R5: flag + canonical f32 params (~32KB)
  // R6 (optional, ws-permitting): xp2 f32 (9.63MB) for fc2 K-split
  u16* tn = (u16*)(ws);
  u16* dcn = tn;
  u16* y2 = tn;
  u16* val = (u16*)(ws + SZ_NC2);
  u16* h = val;                               // 19.27MB chunk spans R1+R2
  u16* om = (u16*)(ws + 2 * SZ_NC2);
  u16* xp1 = (u16*)(ws + 3 * SZ_NC2);
  u16* wT = (u16*)(ws + 4 * SZ_NC2);
  u16* vprojT = wT;                           // fused (708,384) B matrix
  u16* oprojT = wT + 147456 + 124416;
  u16* fc1T = oprojT + 147456;
  u16* fc2T = fc1T + 589824;
  char* r5 = ws + 4 * SZ_NC2 + 3197952;
  int* flag = (int*)r5;
  float* pf = (float*)r5 + 16;
  float* ln1_gF = pf + 0;
  float* ln1_bF = pf + 384;
  float* ln2_gF = pf + 768;
  float* ln2_bF = pf + 1152;
  float* vom_bF = pf + 1536;
  float* oproj_bF = pf + 2304;
  float* fc1_bF = pf + 2688;
  float* fc2_bF = pf + 4224;
  float* xp2 = (float*)(ws + 4 * SZ_NC2 + 3197952 + 65536);
  const size_t need_ksplit =
      4 * SZ_NC2 + 3197952 + 65536 + SZ_NC2 * 2;  // +f32 partial buffer
  const bool ksplit = (ws_size >= need_ksplit);

  probe_kernel<<<1, 64, 0, stream>>>(ln1_g, flag);

  convert_params<<<dim3(6, 9), 256, 0, stream>>>(
      ln1_g, ln1_b, ln2_g, ln2_b, vproj_b, om_b, oproj_b, fc1_b, fc2_b,
      pf, flag);

  convert_weights<<<dim3(576, 5), 256, 0, stream>>>(
      vproj_w, om_w, oproj_w, fc1_w, fc2_w, wT, flag);

  ln1_kernel<<<BB * 49, 256, 0, stream>>>(x, ln1_gF, ln1_bF, tn, flag);

  // fused vproj+om: 64x64 tiles, Mt=196, Ntiles=12 -> 588 blocks
  wgemm_k<4, false, 4, 4><<<588, 256, 0, stream>>>(
      tn, vprojT, vom_bF, nullptr, val, om, 196, 12, 708, 384, 0, flag);

  dcn_kernel<<<(NT * GG) / 16, 256, 0, stream>>>(val, om, dcn);

  // oproj: 32x64 tiles, Mt=392, Ntiles=6 -> 588 blocks
  wgemm_k<2, false, 2, 4><<<588, 256, 0, stream>>>(
      dcn, oprojT, oproj_bF, x, xp1, nullptr, 392, 6, 384, 384, 0, flag);

  ln2_kernel<<<NT / 4, 256, 0, stream>>>(xp1, ln2_gF, ln2_bF, y2);

  // fc1 + fc2 in 2 M-chunks of 6272 rows; h overlays R1+R2
  for (int c = 0; c < 2; c++) {
    int r0 = c * 6272;
    // fc1: 64x64 tiles, Mt=98, Ntiles=24 -> 588 blocks
    wgemm_k<0, true, 4, 4><<<588, 256, 0, stream>>>(
        y2 + (size_t)r0 * CC, fc1T, fc1_bF, nullptr, h, nullptr,
        98, 24, HID, 384, 0, flag);
    if (ksplit) {
      hipMemsetAsync(xp2, 0, (size_t)6272 * 384 * 4, stream);
      // fc2 K-split: 64x64 tiles, grid (147,4): Ks=4 x (98x6 tiles)
      wgemm_k<5, false, 4, 4><<<dim3(147, 4), 256, 0, stream>>>(
          h, fc2T, fc2_bF, nullptr, xp2, nullptr, 98, 6, 384, HID, 0, flag);
      fc2_epi_kernel<<<dim3(98, 6), 256, 0, stream>>>(
          xp2, fc2_bF, xp1, d_out, r0, flag);
    } else {
      // fallback: R5-proven 64x64 MODE3
      wgemm_k<3, false, 4, 4><<<147, 256, 0, stream>>>(
          h, fc2T, fc2_bF, xp1, d_out, nullptr, 98, 6, 384, HID, r0, flag);
    }
  }
}

// Round 9
// 345.268 us; speedup vs baseline: 1.4152x; 1.2921x over previous
//
#include <hip/hip_runtime.h>
#include <math.h>

typedef unsigned short u16;
typedef unsigned int u32;
typedef __bf16 bf16x8 __attribute__((ext_vector_type(8)));
typedef float f32x4 __attribute__((ext_vector_type(4)));

// ---- problem constants ----
#define BB 4
#define CC 384
#define HH 56
#define WW 56
#define GG 12
#define GCC 32
#define KK 9
#define HWD 3136           // H*W
#define NT 12544           // B*H*W tokens
#define HID 1536
#define EPSV 1e-5f

__device__ __forceinline__ float b2f(u16 u) {
  union { float f; u32 u; } c; c.u = ((u32)u) << 16; return c.f;
}
__device__ __forceinline__ u16 f2b(float f) {
  union { float f; u32 u; } c; c.f = f;
  u32 r = c.u + 0x7FFFu + ((c.u >> 16) & 1u);
  return (u16)(r >> 16);
}

// =====================================================================
// Probe: ln1_g[0] == 1.0f exactly -> f32 inputs (flag=1) else bf16.
// =====================================================================
__global__ void probe_kernel(const void* __restrict__ g, int* __restrict__ flag) {
  if (threadIdx.x == 0 && blockIdx.x == 0) {
    u32 u = *(const u32*)g;
    *flag = (u == 0x3F800000u) ? 1 : 0;
  }
}

// =====================================================================
// Fused param conversion -> canonical f32 at fixed offsets.
// =====================================================================
__global__ void convert_params(
    const void* q0, const void* q1, const void* q2, const void* q3,
    const void* q4, const void* q5, const void* q6, const void* q7,
    const void* q8, float* __restrict__ dst, const int* __restrict__ flag) {
  const void* src; int off, n;
  switch (blockIdx.y) {
    case 0: src = q0; off = 0;    n = 384;  break;
    case 1: src = q1; off = 384;  n = 384;  break;
    case 2: src = q2; off = 768;  n = 384;  break;
    case 3: src = q3; off = 1152; n = 384;  break;
    case 4: src = q4; off = 1536; n = 384;  break;
    case 5: src = q5; off = 1920; n = 324;  break;
    case 6: src = q6; off = 2304; n = 384;  break;
    case 7: src = q7; off = 2688; n = 1536; break;
    default: src = q8; off = 4224; n = 384; break;
  }
  int i = blockIdx.x * 256 + threadIdx.x;
  if (i >= n) return;
  float v = (*flag) ? ((const float*)src)[i] : b2f(((const u16*)src)[i]);
  dst[off + i] = v;
}

// =====================================================================
// Fused weight convert+transpose: 5 weights (KxN) -> (NxK) bf16.
// =====================================================================
__global__ void convert_weights(
    const void* w0, const void* w1, const void* w2, const void* w3,
    const void* w4, u16* __restrict__ wT, const int* __restrict__ flag) {
  const void* in; u16* out; int K, N;
  switch (blockIdx.y) {
    case 0: in = w0; out = wT;                      K = 384;  N = 384;  break;
    case 1: in = w1; out = wT + 147456;             K = 384;  N = 324;  break;
    case 2: in = w2; out = wT + 147456 + 124416;    K = 384;  N = 384;  break;
    case 3: in = w3; out = wT + 2*147456 + 124416;  K = 384;  N = 1536; break;
    default: in = w4; out = wT + 2*147456 + 124416 + 589824; K = 1536; N = 384; break;
  }
  int idx = blockIdx.x * 256 + threadIdx.x;
  int kq = K >> 2;
  if (idx >= N * kq) return;
  int n = idx / kq;
  int k4 = (idx - n * kq) << 2;
  u16 e[4];
  if (*flag) {
    const float* f = (const float*)in;
#pragma unroll
    for (int r = 0; r < 4; r++) e[r] = f2b(f[(size_t)(k4 + r) * N + n]);
  } else {
    const u16* hh = (const u16*)in;
#pragma unroll
    for (int r = 0; r < 4; r++) e[r] = hh[(size_t)(k4 + r) * N + n];
  }
  uint2 pk;
  pk.x = (u32)e[0] | ((u32)e[1] << 16);
  pk.y = (u32)e[2] | ((u32)e[3] << 16);
  *reinterpret_cast<uint2*>(&out[(size_t)n * K + k4]) = pk;
}

// =====================================================================
// LN1 + NCHW->NHWC transpose; also emits xp0 = x in (NT,C) bf16.
// =====================================================================
__global__ __launch_bounds__(256) void ln1_kernel(
    const void* __restrict__ x, const float* __restrict__ gam,
    const float* __restrict__ bet, u16* __restrict__ tn,
    u16* __restrict__ xp0, const int* __restrict__ flag) {
  __shared__ u16 tile[64 * 385];
  const int t = threadIdx.x;
  const int blk = blockIdx.x;
  const int b = blk / 49;
  const int hw0 = (blk - b * 49) * 64;
  const int dtf = *flag;

  const int cofs = t >> 3;
  const int hofs = (t & 7) * 8;
  if (dtf) {
    const float* xf = (const float*)x;
#pragma unroll
    for (int it = 0; it < 12; it++) {
      int cc = it * 32 + cofs;
      size_t base = ((size_t)b * CC + cc) * HWD + hw0 + hofs;
      float4 a0 = *reinterpret_cast<const float4*>(&xf[base]);
      float4 a1 = *reinterpret_cast<const float4*>(&xf[base + 4]);
      tile[(hofs + 0) * 385 + cc] = f2b(a0.x);
      tile[(hofs + 1) * 385 + cc] = f2b(a0.y);
      tile[(hofs + 2) * 385 + cc] = f2b(a0.z);
      tile[(hofs + 3) * 385 + cc] = f2b(a0.w);
      tile[(hofs + 4) * 385 + cc] = f2b(a1.x);
      tile[(hofs + 5) * 385 + cc] = f2b(a1.y);
      tile[(hofs + 6) * 385 + cc] = f2b(a1.z);
      tile[(hofs + 7) * 385 + cc] = f2b(a1.w);
    }
  } else {
    const u16* xh = (const u16*)x;
#pragma unroll
    for (int it = 0; it < 12; it++) {
      int cc = it * 32 + cofs;
      uint4 v = *reinterpret_cast<const uint4*>(
          &xh[((size_t)b * CC + cc) * HWD + hw0 + hofs]);
      u32 uu[4] = {v.x, v.y, v.z, v.w};
#pragma unroll
      for (int r = 0; r < 4; r++) {
        tile[(hofs + 2 * r + 0) * 385 + cc] = (u16)(uu[r] & 0xFFFFu);
        tile[(hofs + 2 * r + 1) * 385 + cc] = (u16)(uu[r] >> 16);
      }
    }
  }
  __syncthreads();

  const int lane = t & 63;
  const int wv = t >> 6;
  for (int tk = wv; tk < 64; tk += 4) {
    float v[6];
    float s = 0.f;
#pragma unroll
    for (int j = 0; j < 6; j++) {
      v[j] = b2f(tile[tk * 385 + j * 64 + lane]);
      s += v[j];
    }
#pragma unroll
    for (int off = 32; off > 0; off >>= 1) s += __shfl_xor(s, off);
    float mu = s * (1.f / 384.f);
    float q = 0.f;
#pragma unroll
    for (int j = 0; j < 6; j++) {
      float d = v[j] - mu;
      q += d * d;
    }
#pragma unroll
    for (int off = 32; off > 0; off >>= 1) q += __shfl_xor(q, off);
    float rs = rsqrtf(q * (1.f / 384.f) + EPSV);
    size_t row = ((size_t)b * HWD + hw0 + tk) * CC;
#pragma unroll
    for (int j = 0; j < 6; j++) {
      int cc = j * 64 + lane;
      float y = (v[j] - mu) * rs * gam[cc] + bet[cc];
      tn[row + cc] = f2b(y);
      xp0[row + cc] = f2b(v[j]);
    }
  }
}

// =====================================================================
// LN2: xp1 (NT,C) bf16 -> y2 bf16. One wave per token.
// =====================================================================
__global__ __launch_bounds__(256) void ln2_kernel(
    const u16* __restrict__ xp1, const float* __restrict__ gam,
    const float* __restrict__ bet, u16* __restrict__ y2) {
  const int tok = blockIdx.x * 4 + (threadIdx.x >> 6);
  const int lane = threadIdx.x & 63;
  const u16* row = xp1 + (size_t)tok * CC;
  float v[6];
  float s = 0.f;
#pragma unroll
  for (int j = 0; j < 6; j++) {
    v[j] = b2f(row[j * 64 + lane]);
    s += v[j];
  }
#pragma unroll
  for (int off = 32; off > 0; off >>= 1) s += __shfl_xor(s, off);
  float mu = s * (1.f / 384.f);
  float q = 0.f;
#pragma unroll
  for (int j = 0; j < 6; j++) {
    float d = v[j] - mu;
    q += d * d;
  }
#pragma unroll
  for (int off = 32; off > 0; off >>= 1) q += __shfl_xor(q, off);
  float rs = rsqrtf(q * (1.f / 384.f) + EPSV);
#pragma unroll
  for (int j = 0; j < 6; j++) {
    int cc = j * 64 + lane;
    y2[(size_t)tok * CC + cc] = f2b((v[j] - mu) * rs * gam[cc] + bet[cc]);
  }
}

// =====================================================================
// DCNv4 sampling. om bf16 padded: token stride 336, group stride 28.
// =====================================================================
__global__ __launch_bounds__(256) void dcn_kernel(
    const u16* __restrict__ val, const u16* __restrict__ om,
    u16* __restrict__ dcn) {
  const int t = threadIdx.x;
  const int u = blockIdx.x * 16 + (t >> 4);
  const int l = t & 15;
  const int g = u % GG;
  const int bhw = u / GG;
  const int hw = bhw % HWD;
  const int b = bhw / HWD;
  const int wx = hw % WW;
  const int hy = hw / WW;

  const u16* o = om + (size_t)bhw * 336 + g * 28;
  uint2 q[7];
#pragma unroll
  for (int i = 0; i < 7; i++)
    q[i] = *reinterpret_cast<const uint2*>(o + 4 * i);
  float ov[28];
#pragma unroll
  for (int i = 0; i < 7; i++) {
    ov[4 * i + 0] = b2f((u16)(q[i].x & 0xFFFFu));
    ov[4 * i + 1] = b2f((u16)(q[i].x >> 16));
    ov[4 * i + 2] = b2f((u16)(q[i].y & 0xFFFFu));
    ov[4 * i + 3] = b2f((u16)(q[i].y >> 16));
  }

  const u16* vb = val + (size_t)b * HWD * CC + g * GCC + l * 2;
  float acc0 = 0.f, acc1 = 0.f;
#pragma unroll
  for (int k = 0; k < KK; k++) {
    float dx = ov[2 * k];
    float dy = ov[2 * k + 1];
    float mw = ov[18 + k];
    float px = (float)(wx + (k % 3) - 1) + dx;
    float py = (float)(hy + (k / 3) - 1) + dy;
    float x0f = floorf(px), y0f = floorf(py);
    float tx = px - x0f, ty = py - y0f;
    int x0 = (int)x0f, y0 = (int)y0f;
    int x1 = x0 + 1, y1 = y0 + 1;
    bool xv0 = (x0 >= 0) && (x0 < WW);
    bool xv1 = (x1 >= 0) && (x1 < WW);
    bool yv0 = (y0 >= 0) && (y0 < HH);
    bool yv1 = (y1 >= 0) && (y1 < HH);
    int xc0 = min(max(x0, 0), WW - 1), xc1 = min(max(x1, 0), WW - 1);
    int yc0 = min(max(y0, 0), HH - 1), yc1 = min(max(y1, 0), HH - 1);
    u32 c00 = *reinterpret_cast<const u32*>(&vb[(size_t)(yc0 * WW + xc0) * CC]);
    u32 c01 = *reinterpret_cast<const u32*>(&vb[(size_t)(yc0 * WW + xc1) * CC]);
    u32 c10 = *reinterpret_cast<const u32*>(&vb[(size_t)(yc1 * WW + xc0) * CC]);
    u32 c11 = *reinterpret_cast<const u32*>(&vb[(size_t)(yc1 * WW + xc1) * CC]);
    float w00 = (yv0 && xv0) ? (1.f - tx) * (1.f - ty) : 0.f;
    float w01 = (yv0 && xv1) ? tx * (1.f - ty) : 0.f;
    float w10 = (yv1 && xv0) ? (1.f - tx) * ty : 0.f;
    float w11 = (yv1 && xv1) ? tx * ty : 0.f;
    float s0 = w00 * b2f((u16)(c00 & 0xFFFFu)) + w01 * b2f((u16)(c01 & 0xFFFFu)) +
               w10 * b2f((u16)(c10 & 0xFFFFu)) + w11 * b2f((u16)(c11 & 0xFFFFu));
    float s1 = w00 * b2f((u16)(c00 >> 16)) + w01 * b2f((u16)(c01 >> 16)) +
               w10 * b2f((u16)(c10 >> 16)) + w11 * b2f((u16)(c11 >> 16));
    acc0 += mw * s0;
    acc1 += mw * s1;
  }
  u32 pk = (u32)f2b(acc0) | ((u32)f2b(acc1) << 16);
  *reinterpret_cast<u32*>(&dcn[(size_t)bhw * CC + g * GCC + l * 2]) = pk;
}

// =====================================================================
// Barrier-free wave-GEMM (64-row strips), 2-stage register dbuf K-loop.
// MODE 4: fused vproj+om (n<384 -> val bf16 ld384; else om bf16 padded).
// MODE 2: bf16 out (ld 384) + bf16 residual from xp0 (NT,C).
// =====================================================================
template <int MODE, int MI, int NI>
__global__ __launch_bounds__(256) void wgemm_k(
    const u16* __restrict__ A, const u16* __restrict__ Wt,
    const float* __restrict__ bias, const u16* __restrict__ res,
    void* __restrict__ out, void* __restrict__ out2,
    int Mt, int Ntiles, int Nn, int K) {
  const int t = threadIdx.x;
  const int wv = t >> 6;
  const int lane = t & 63;
  const int fr = lane & 15;
  const int quad = lane >> 4;
  const int tile = blockIdx.x * 4 + wv;
  const int mt = tile / Ntiles;
  const int nt = tile - mt * Ntiles;
  if (mt >= Mt) return;
  const int m0 = mt * (MI * 16);
  const int n0 = nt * (NI * 16);

  f32x4 acc[MI][NI];
#pragma unroll
  for (int mi = 0; mi < MI; mi++)
#pragma unroll
    for (int ni = 0; ni < NI; ni++) acc[mi][ni] = f32x4{0.f, 0.f, 0.f, 0.f};

  const u16* Ap = A + (size_t)(m0 + fr) * K + quad * 8;
  const u16* Bp = Wt + (size_t)(n0 + fr) * K + quad * 8;

  bf16x8 a0[MI], b0[NI], a1[MI], b1[NI];
#pragma unroll
  for (int mi = 0; mi < MI; mi++)
    a0[mi] = *reinterpret_cast<const bf16x8*>(Ap + (size_t)(mi * 16) * K);
#pragma unroll
  for (int ni = 0; ni < NI; ni++)
    b0[ni] = *reinterpret_cast<const bf16x8*>(Bp + (size_t)(ni * 16) * K);

  for (int kb = 0; kb < K; kb += 64) {
#pragma unroll
    for (int mi = 0; mi < MI; mi++)
      a1[mi] = *reinterpret_cast<const bf16x8*>(Ap + (size_t)(mi * 16) * K + kb + 32);
#pragma unroll
    for (int ni = 0; ni < NI; ni++)
      b1[ni] = *reinterpret_cast<const bf16x8*>(Bp + (size_t)(ni * 16) * K + kb + 32);
#pragma unroll
    for (int mi = 0; mi < MI; mi++)
#pragma unroll
      for (int ni = 0; ni < NI; ni++)
        acc[mi][ni] = __builtin_amdgcn_mfma_f32_16x16x32_bf16(
            a0[mi], b0[ni], acc[mi][ni], 0, 0, 0);
    if (kb + 64 < K) {
#pragma unroll
      for (int mi = 0; mi < MI; mi++)
        a0[mi] = *reinterpret_cast<const bf16x8*>(Ap + (size_t)(mi * 16) * K + kb + 64);
#pragma unroll
      for (int ni = 0; ni < NI; ni++)
        b0[ni] = *reinterpret_cast<const bf16x8*>(Bp + (size_t)(ni * 16) * K + kb + 64);
    }
#pragma unroll
    for (int mi = 0; mi < MI; mi++)
#pragma unroll
      for (int ni = 0; ni < NI; ni++)
        acc[mi][ni] = __builtin_amdgcn_mfma_f32_16x16x32_bf16(
            a1[mi], b1[ni], acc[mi][ni], 0, 0, 0);
  }

  float bias_v[NI];
#pragma unroll
  for (int ni = 0; ni < NI; ni++) {
    int n = n0 + ni * 16 + fr;
    bias_v[ni] = (n < Nn) ? bias[n] : 0.f;
  }

#pragma unroll
  for (int mi = 0; mi < MI; mi++) {
#pragma unroll
    for (int ni = 0; ni < NI; ni++) {
      int n = n0 + ni * 16 + fr;
      int mbase = m0 + mi * 16 + quad * 4;
      if (MODE == 4) {
        if (n < 384) {
#pragma unroll
          for (int r = 0; r < 4; r++)
            ((u16*)out)[(size_t)(mbase + r) * 384 + n] =
                f2b(acc[mi][ni][r] + bias_v[ni]);
        } else if (n < 708) {
          int lin = n - 384;
          int g = lin / 27;
          int s = lin - g * 27;
#pragma unroll
          for (int r = 0; r < 4; r++)
            ((u16*)out2)[(size_t)(mbase + r) * 336 + g * 28 + s] =
                f2b(acc[mi][ni][r] + bias_v[ni]);
        }
      } else {  // MODE 2: bf16 out + bf16 residual (row-major xp0)
#pragma unroll
        for (int r = 0; r < 4; r++) {
          float vv = acc[mi][ni][r] + bias_v[ni] +
                     b2f(res[(size_t)(mbase + r) * 384 + n]);
          ((u16*)out)[(size_t)(mbase + r) * 384 + n] = f2b(vv);
        }
      }
    }
  }
}

// =====================================================================
// Fused MLP: out = gelu(y2 @ fc1 + b1) @ fc2 + b2 + xp1, stored NCHW.
// One block per 64-token strip (196 blocks). h never touches HBM:
// per hid-chunk of 384, each wave computes h cols [wv*96,+96) in regs,
// gelu -> LDS (64x392 padded bf16), then accumulates its out cols
// [wv*96,+96) from the LDS chunk. 4 chunks, 8 barriers.
// =====================================================================
__global__ __launch_bounds__(256, 1) void mlp_kernel(
    const u16* __restrict__ y2, const u16* __restrict__ fc1T,
    const u16* __restrict__ fc2T, const float* __restrict__ b1,
    const float* __restrict__ b2, const u16* __restrict__ xp1,
    void* __restrict__ out, const int* __restrict__ flag) {
  __shared__ u16 hs[64 * 392];
  const int t = threadIdx.x;
  const int wv = t >> 6;
  const int lane = t & 63;
  const int fr = lane & 15;
  const int quad = lane >> 4;
  const int m0 = blockIdx.x * 64;
  const int nw = wv * 96;              // this wave's 96 output cols

  f32x4 accO[4][6];
#pragma unroll
  for (int mi = 0; mi < 4; mi++)
#pragma unroll
    for (int ni = 0; ni < 6; ni++) accO[mi][ni] = f32x4{0.f, 0.f, 0.f, 0.f};

  const u16* Ap = y2 + (size_t)(m0 + fr) * 384 + quad * 8;

  for (int kc = 0; kc < 4; kc++) {
    const int hbase = kc * 384;
    // ---- fc1: h[:, hbase+nw .. +96] into regs ----
    f32x4 accH[4][6];
#pragma unroll
    for (int mi = 0; mi < 4; mi++)
#pragma unroll
      for (int ni = 0; ni < 6; ni++) accH[mi][ni] = f32x4{0.f, 0.f, 0.f, 0.f};
    const u16* Bp1 = fc1T + (size_t)(hbase + nw + fr) * 384 + quad * 8;
    {
      bf16x8 a0[4], b0[6], a1[4], b1v[6];
#pragma unroll
      for (int mi = 0; mi < 4; mi++)
        a0[mi] = *reinterpret_cast<const bf16x8*>(Ap + (size_t)(mi * 16) * 384);
#pragma unroll
      for (int ni = 0; ni < 6; ni++)
        b0[ni] = *reinterpret_cast<const bf16x8*>(Bp1 + (size_t)(ni * 16) * 384);
      for (int kb = 0; kb < 384; kb += 64) {
#pragma unroll
        for (int mi = 0; mi < 4; mi++)
          a1[mi] = *reinterpret_cast<const bf16x8*>(Ap + (size_t)(mi * 16) * 384 + kb + 32);
#pragma unroll
        for (int ni = 0; ni < 6; ni++)
          b1v[ni] = *reinterpret_cast<const bf16x8*>(Bp1 + (size_t)(ni * 16) * 384 + kb + 32);
#pragma unroll
        for (int mi = 0; mi < 4; mi++)
#pragma unroll
          for (int ni = 0; ni < 6; ni++)
            accH[mi][ni] = __builtin_amdgcn_mfma_f32_16x16x32_bf16(
                a0[mi], b0[ni], accH[mi][ni], 0, 0, 0);
        if (kb + 64 < 384) {
#pragma unroll
          for (int mi = 0; mi < 4; mi++)
            a0[mi] = *reinterpret_cast<const bf16x8*>(Ap + (size_t)(mi * 16) * 384 + kb + 64);
#pragma unroll
          for (int ni = 0; ni < 6; ni++)
            b0[ni] = *reinterpret_cast<const bf16x8*>(Bp1 + (size_t)(ni * 16) * 384 + kb + 64);
        }
#pragma unroll
        for (int mi = 0; mi < 4; mi++)
#pragma unroll
          for (int ni = 0; ni < 6; ni++)
            accH[mi][ni] = __builtin_amdgcn_mfma_f32_16x16x32_bf16(
                a1[mi], b1v[ni], accH[mi][ni], 0, 0, 0);
      }
    }
    // ---- gelu + LDS store ----
    __syncthreads();   // prior chunk's LDS reads done before overwrite
#pragma unroll
    for (int mi = 0; mi < 4; mi++) {
#pragma unroll
      for (int ni = 0; ni < 6; ni++) {
        int col = nw + ni * 16 + fr;
        float bb = b1[hbase + col];
        int rowb = mi * 16 + quad * 4;
#pragma unroll
        for (int r = 0; r < 4; r++) {
          float vv = accH[mi][ni][r] + bb;
          vv = 0.5f * vv * (1.0f + erff(vv * 0.70710678118654752f));
          hs[(rowb + r) * 392 + col] = f2b(vv);
        }
      }
    }
    __syncthreads();
    // ---- fc2 partial: accO += h_chunk @ fc2T[nw-cols, hbase-rows] ----
    const u16* Bp2 = fc2T + (size_t)(nw + fr) * 1536 + hbase + quad * 8;
    {
      bf16x8 b0[6], b1v[6];
#pragma unroll
      for (int ni = 0; ni < 6; ni++)
        b0[ni] = *reinterpret_cast<const bf16x8*>(Bp2 + (size_t)(ni * 16) * 1536);
      for (int kb = 0; kb < 384; kb += 64) {
#pragma unroll
        for (int ni = 0; ni < 6; ni++)
          b1v[ni] = *reinterpret_cast<const bf16x8*>(Bp2 + (size_t)(ni * 16) * 1536 + kb + 32);
        {
          bf16x8 av[4];
#pragma unroll
          for (int mi = 0; mi < 4; mi++)
            av[mi] = *reinterpret_cast<const bf16x8*>(
                &hs[(mi * 16 + fr) * 392 + quad * 8 + kb]);
#pragma unroll
          for (int mi = 0; mi < 4; mi++)
#pragma unroll
            for (int ni = 0; ni < 6; ni++)
              accO[mi][ni] = __builtin_amdgcn_mfma_f32_16x16x32_bf16(
                  av[mi], b0[ni], accO[mi][ni], 0, 0, 0);
        }
        if (kb + 64 < 384) {
#pragma unroll
          for (int ni = 0; ni < 6; ni++)
            b0[ni] = *reinterpret_cast<const bf16x8*>(Bp2 + (size_t)(ni * 16) * 1536 + kb + 64);
        }
        {
          bf16x8 av[4];
#pragma unroll
          for (int mi = 0; mi < 4; mi++)
            av[mi] = *reinterpret_cast<const bf16x8*>(
                &hs[(mi * 16 + fr) * 392 + quad * 8 + kb + 32]);
#pragma unroll
          for (int mi = 0; mi < 4; mi++)
#pragma unroll
            for (int ni = 0; ni < 6; ni++)
              accO[mi][ni] = __builtin_amdgcn_mfma_f32_16x16x32_bf16(
                  av[mi], b1v[ni], accO[mi][ni], 0, 0, 0);
        }
      }
    }
  }

  // ---- epilogue: + bias + xp1 residual -> NCHW out ----
  const int dtf = *flag;
#pragma unroll
  for (int mi = 0; mi < 4; mi++) {
#pragma unroll
    for (int ni = 0; ni < 6; ni++) {
      int n = nw + ni * 16 + fr;
      int mbase = m0 + mi * 16 + quad * 4;
      int b = mbase / HWD;
      int hw = mbase - b * HWD;
      float bb = b2[n];
      float vv[4];
#pragma unroll
      for (int r = 0; r < 4; r++)
        vv[r] = accO[mi][ni][r] + bb + b2f(xp1[(size_t)(mbase + r) * 384 + n]);
      if (dtf) {
        float4 st = make_float4(vv[0], vv[1], vv[2], vv[3]);
        *reinterpret_cast<float4*>(
            &((float*)out)[((size_t)b * CC + n) * HWD + hw]) = st;
      } else {
        uint2 st;
        st.x = (u32)f2b(vv[0]) | ((u32)f2b(vv[1]) << 16);
        st.y = (u32)f2b(vv[2]) | ((u32)f2b(vv[3]) << 16);
        *reinterpret_cast<uint2*>(
            &((u16*)out)[((size_t)b * CC + n) * HWD + hw]) = st;
      }
    }
  }
}

// =====================================================================
extern "C" void kernel_launch(void* const* d_in, const int* in_sizes, int n_in,
                              void* d_out, int out_size, void* d_ws,
                              size_t ws_size, hipStream_t stream) {
  const void* x = d_in[0];
  const void* ln1_g = d_in[1];
  const void* ln1_b = d_in[2];
  const void* vproj_w = d_in[3];
  const void* vproj_b = d_in[4];
  const void* om_w = d_in[5];
  const void* om_b = d_in[6];
  const void* oproj_w = d_in[7];
  const void* oproj_b = d_in[8];
  const void* ln2_g = d_in[9];
  const void* ln2_b = d_in[10];
  const void* fc1_w = d_in[11];
  const void* fc1_b = d_in[12];
  const void* fc2_w = d_in[13];
  const void* fc2_b = d_in[14];

  char* ws = (char*)d_ws;
  const size_t SZ_NC2 = (size_t)NT * CC * 2;     // 9,633,792
  const size_t SZ_OM2 = (size_t)NT * 336 * 2;    // 8,429,568
  // R0: tn -> dcn -> y2 | R1: val | R2: om bf16 | R3: xp1 | R4: xp0
  // R5: weights | R6: flag+params. Total ~50.2MB (< proven 51.5MB).
  u16* tn = (u16*)(ws);
  u16* dcn = tn;
  u16* y2 = tn;
  u16* val = (u16*)(ws + SZ_NC2);
  u16* om = (u16*)(ws + 2 * SZ_NC2);
  u16* xp1 = (u16*)(ws + 2 * SZ_NC2 + SZ_OM2);
  u16* xp0 = (u16*)(ws + 3 * SZ_NC2 + SZ_OM2);
  u16* wT = (u16*)(ws + 4 * SZ_NC2 + SZ_OM2);
  u16* vprojT = wT;                              // fused (708,384)
  u16* oprojT = wT + 147456 + 124416;
  u16* fc1T = oprojT + 147456;
  u16* fc2T = fc1T + 589824;
  char* r6 = ws + 4 * SZ_NC2 + SZ_OM2 + 3197952;
  int* flag = (int*)r6;
  float* pf = (float*)r6 + 16;
  float* ln1_gF = pf + 0;
  float* ln1_bF = pf + 384;
  float* ln2_gF = pf + 768;
  float* ln2_bF = pf + 1152;
  float* vom_bF = pf + 1536;
  float* oproj_bF = pf + 2304;
  float* fc1_bF = pf + 2688;
  float* fc2_bF = pf + 4224;

  probe_kernel<<<1, 64, 0, stream>>>(ln1_g, flag);

  convert_params<<<dim3(6, 9), 256, 0, stream>>>(
      ln1_g, ln1_b, ln2_g, ln2_b, vproj_b, om_b, oproj_b, fc1_b, fc2_b,
      pf, flag);

  convert_weights<<<dim3(576, 5), 256, 0, stream>>>(
      vproj_w, om_w, oproj_w, fc1_w, fc2_w, wT, flag);

  ln1_kernel<<<BB * 49, 256, 0, stream>>>(x, ln1_gF, ln1_bF, tn, xp0, flag);

  // fused vproj+om: 64x64 tiles, Mt=196, Ntiles=12 -> 588 blocks
  wgemm_k<4, 4, 4><<<588, 256, 0, stream>>>(
      tn, vprojT, vom_bF, nullptr, val, om, 196, 12, 708, 384);

  dcn_kernel<<<(NT * GG) / 16, 256, 0, stream>>>(val, om, dcn);

  // oproj: 32x64 tiles, Mt=392, Ntiles=6 -> 588 blocks; residual = xp0
  wgemm_k<2, 2, 4><<<588, 256, 0, stream>>>(
      dcn, oprojT, oproj_bF, xp0, xp1, nullptr, 392, 6, 384, 384);

  ln2_kernel<<<NT / 4, 256, 0, stream>>>(xp1, ln2_gF, ln2_bF, y2);

  // fused fc1+gelu+fc2+residual: 196 blocks, h stays on-chip
  mlp_kernel<<<196, 256, 0, stream>>>(
      y2, fc1T, fc2T, fc1_bF, fc2_bF, xp1, d_out, flag);
}